// Round 2
// baseline (823.992 us; speedup 1.0000x reference)
//
#include <hip/hip_runtime.h>
#include <math.h>

#define CCH   128        // C
#define C2    64         // C/2
#define C2X   256        // 2C
#define CR    8          // C/16
#define HW    16384
#define NB    16
#define EPSB  1e-5f

// workspace layout (float offsets) -- blob lives in d_out, NOT here
#define WS_POOLED 0          // 4096
#define WS_WCH    4096       // 2048
#define WS_AVGS   6144       // 2048
#define WS_MAXB   8192       // 2048 (uint bits)
#define WS_CA     10240      // 2048
#define WS_BC     12288      // 128
#define WS_WV     16384      // 131072 floats worth (262144 bf16)  [n][o][c]
#define WS_WI     147456     // 131072
#define WS_SPMEAN 278528     // 262144
#define WS_SPMAX  540672     // 262144
#define WS_SA     802816     // 262144

typedef short short8 __attribute__((ext_vector_type(8)));
typedef float floatx4 __attribute__((ext_vector_type(4)));
typedef unsigned short ushort_t;
typedef unsigned int uint_t;

#define GAS __attribute__((address_space(1)))
#define LAS __attribute__((address_space(3)))

__device__ __forceinline__ void gload16(const void* g, void* l) {
    __builtin_amdgcn_global_load_lds((const GAS void*)g, (LAS void*)l, 16, 0, 0);
}

__device__ __forceinline__ float sigmoidf_(float x) {
    return 1.0f / (1.0f + __expf(-x));
}

// fp32 -> bf16 with round-to-nearest-even
__device__ __forceinline__ uint_t f2bf(float f) {
    uint_t u = __float_as_uint(f);
    return (u + 0x7FFFu + ((u >> 16) & 1u)) >> 16;
}
__device__ __forceinline__ uint_t pack2bf(float a, float b) {
    return f2bf(a) | (f2bf(b) << 16);
}

// ---------------------------------------------------------------- zero pooled accumulator
__global__ void k_zero(float* __restrict__ p) {
    p[blockIdx.x * 256 + threadIdx.x] = 0.f;
}

// ---------------------------------------------------------------- fused pool + bf16 cast + transpose
// One block = (n, pt, stream): 128c x 128p fp32 in -> 32 KB pre-swizzled bf16 blob out
// Blob content: blob[p*256B + (cidx^(p&7))*16B] = bf16{X[p][8cidx..8cidx+7]}
// -> k_conv DMAs it LINEARLY into LDS and reads fragments with the same XOR (bank-clean).
// Channel means accumulated via wave shuffle + 1 atomic per (wave,channel).
__global__ __launch_bounds__(256)
void k_prep(const float* __restrict__ fvi, const float* __restrict__ fir,
            ushort_t* __restrict__ blob, float* __restrict__ pooled) {
    int b  = blockIdx.x;                 // ((n*128+pt)*2+st)
    int st = b & 1;
    int pt = (b >> 1) & 127;
    int n  = b >> 8;
    const float* src = (st == 0 ? fvi : fir) + (size_t)n * CCH * HW + pt * 128;
    __shared__ __align__(16) ushort_t img[128 * 128];   // 32 KB blob image
    int t = threadIdx.x;
    int p = t & 127;                     // pixel within tile
    int cg = t >> 7;                     // 0/1 -> chunk half
    const float inv = 1.0f / HW;
    #pragma unroll
    for (int i = 0; i < 8; ++i) {
        int cidx = cg * 8 + i;           // 16-byte chunk id = channels 8cidx..8cidx+7
        const float* sc = src + (size_t)(cidx * 8) * HW + p;
        // 8 coalesced dword loads (lanes = consecutive p), fully independent
        float v0 = sc[0];        float v1 = sc[HW];
        float v2 = sc[2 * HW];   float v3 = sc[3 * HW];
        float v4 = sc[4 * HW];   float v5 = sc[5 * HW];
        float v6 = sc[6 * HW];   float v7 = sc[7 * HW];
        uint4 pk;
        pk.x = pack2bf(v0, v1);  pk.y = pack2bf(v2, v3);
        pk.z = pack2bf(v4, v5);  pk.w = pack2bf(v6, v7);
        // XOR-swizzled write: lanes have consecutive p -> all 8 bank-quads hit
        *(uint4*)&img[p * 128 + ((cidx ^ (p & 7)) << 3)] = pk;
        // channel sums: each wave holds one channel across its 64 lanes
        float ss[8] = {v0, v1, v2, v3, v4, v5, v6, v7};
        #pragma unroll
        for (int j = 0; j < 8; ++j) {
            float s = ss[j] * inv;
            #pragma unroll
            for (int off = 1; off < 64; off <<= 1)
                s += __shfl_xor(s, off, 64);
            if ((t & 63) == 0)
                atomicAdd(&pooled[n * 256 + st * 128 + cidx * 8 + j], s);
        }
    }
    __syncthreads();
    // linear 32 KB dump: perfectly coalesced 16B/lane stores
    ushort_t* dst = blob + (size_t)b * 16384;
    #pragma unroll
    for (int j = 0; j < 8; ++j) {
        int off = (j * 256 + t) * 8;
        *(uint4*)&dst[off] = *(const uint4*)&img[off];
    }
}

// ---------------------------------------------------------------- channel-attention MLP -> wch
__global__ void k_wch(const float* __restrict__ pooled,
                      const float* __restrict__ ca1_w, const float* __restrict__ ca1_b,
                      const float* __restrict__ ag, const float* __restrict__ ab,
                      const float* __restrict__ am, const float* __restrict__ av,
                      const float* __restrict__ ca2_w, const float* __restrict__ ca2_b,
                      const float* __restrict__ bg, const float* __restrict__ bb,
                      const float* __restrict__ bm, const float* __restrict__ bv,
                      float* __restrict__ wch) {
    int n = blockIdx.x;
    int t = threadIdx.x;            // 128 threads
    __shared__ float h[C2];
    if (t < C2) {
        float acc = ca1_b[t];
        const float* w = ca1_w + t * C2X;
        const float* p = pooled + n * C2X;
        for (int k = 0; k < C2X; k++) acc += w[k] * p[k];
        float s = ag[t] * rsqrtf(av[t] + EPSB);
        acc = (acc - am[t]) * s + ab[t];
        h[t] = fmaxf(acc, 0.f);
    }
    __syncthreads();
    float acc = ca2_b[t];
    const float* w = ca2_w + t * C2;
    for (int j = 0; j < C2; j++) acc += w[j] * h[j];
    float s = bg[t] * rsqrtf(bv[t] + EPSB);
    acc = (acc - bm[t]) * s + bb[t];
    wch[n * CCH + t] = sigmoidf_(acc);
}

// ---------------------------------------------------------------- per-batch effective bf16 conv weights
__global__ void k_mkweights(const float* __restrict__ wch, const float* __restrict__ conv1_w,
                            const float* __restrict__ cg, const float* __restrict__ cb,
                            const float* __restrict__ cm, const float* __restrict__ cv,
                            const float* __restrict__ conv1_b,
                            ushort_t* __restrict__ Wv, ushort_t* __restrict__ Wi,
                            float* __restrict__ Bc, float* __restrict__ zeroreg) {
    int b = blockIdx.x;             // n*128 + o
    int t = threadIdx.x;            // 128 = c
    if (b < 16) { zeroreg[b * 256 + t] = 0.f; zeroreg[b * 256 + 128 + t] = 0.f; }
    if (b == 16) {
        float A = cg[t] * rsqrtf(cv[t] + EPSB);
        Bc[t] = A * (conv1_b[t] - cm[t]) + cb[t];
    }
    int n = b >> 7, o = b & 127;
    float A  = cg[o] * rsqrtf(cv[o] + EPSB);
    float u  = wch[n * CCH + t];
    float w0 = conv1_w[o * C2X + t];
    float w1 = conv1_w[o * C2X + t + CCH];
    Wv[(size_t)b * CCH + t] = (ushort_t)f2bf(A * (w0 + u * w1));
    Wi[(size_t)b * CCH + t] = (ushort_t)f2bf(A * (w1 + u * w0));
}

// ---------------------------------------------------------------- fused conv1x1+bn+relu + reductions (MFMA)
// v2: A-frags (weights) in registers from L2-hot Wv/Wi; X arrives via LINEAR
// global_load_lds DMA of the pre-swizzled blob (64 KB per block); counted
// vmcnt(8) + raw s_barrier keeps the Xi half in flight under the Xv compute.
__global__ __launch_bounds__(256)
void k_conv_reduce(const ushort_t* __restrict__ blob,
                   const ushort_t* __restrict__ Wv, const ushort_t* __restrict__ Wi,
                   const float* __restrict__ Bc,
                   float* __restrict__ avgsum, uint_t* __restrict__ maxbits,
                   float* __restrict__ spmean, float* __restrict__ spmax) {
    int n  = blockIdx.x >> 7;
    int pt = blockIdx.x & 127;
    int p0 = pt * 128;
    __shared__ __align__(16) ushort_t sX[32768];   // 64 KB: Xv [0,16384), Xi [16384,32768)
    int tid  = threadIdx.x;
    int wave = tid >> 6;
    int lane = tid & 63;
    int q    = lane >> 4;
    int ln   = lane & 15;

    // ---- A fragments straight to registers (each byte of 64 KB read once per block, L2-hot)
    short8 aF[2][8];
    {
        const ushort_t* wv = Wv + (size_t)n * 16384;
        const ushort_t* wi = Wi + (size_t)n * 16384;
        #pragma unroll
        for (int kc = 0; kc < 8; ++kc) {
            const ushort_t* ws_ = (kc < 4) ? wv : wi;
            #pragma unroll
            for (int ot = 0; ot < 2; ++ot) {
                int o = wave * 32 + ot * 16 + ln;
                aF[ot][kc] = *(const short8*)&ws_[(size_t)o * 128 + (kc & 3) * 32 + q * 8];
            }
        }
    }
    __builtin_amdgcn_sched_barrier(0);    // pin: A-loads issue before the DMAs (vmcnt counting)
    // ---- async DMA: blob(n,pt) 64 KB -> LDS, Xv issues first, then Xi
    {
        const ushort_t* gb = blob + (((size_t)(n * 128 + pt)) << 15) + wave * 512 + lane * 8;
        ushort_t* lb = &sX[wave * 512];
        #pragma unroll
        for (int i = 0; i < 16; ++i)
            gload16(gb + i * 2048, lb + i * 2048);
    }
    __builtin_amdgcn_sched_barrier(0);

    floatx4 acc[2][8];
    #pragma unroll
    for (int a = 0; a < 2; a++)
        #pragma unroll
        for (int c = 0; c < 8; c++) acc[a][c] = (floatx4){0.f, 0.f, 0.f, 0.f};

    // phase 0: A(16)+DMA(16) outstanding; vmcnt(8) -> A done + Xv landed, Xi in flight
    asm volatile("s_waitcnt vmcnt(8)" ::: "memory");
    __builtin_amdgcn_s_barrier();
    __builtin_amdgcn_sched_barrier(0);
    #pragma unroll
    for (int kc = 0; kc < 4; ++kc) {
        #pragma unroll
        for (int pj = 0; pj < 8; ++pj) {
            int p = pj * 16 + ln;
            int cidx = kc * 4 + q;
            short8 bX = *(const short8*)&sX[p * 128 + ((cidx ^ (p & 7)) << 3)];
            acc[0][pj] = __builtin_amdgcn_mfma_f32_16x16x32_bf16(aF[0][kc], bX, acc[0][pj], 0, 0, 0);
            acc[1][pj] = __builtin_amdgcn_mfma_f32_16x16x32_bf16(aF[1][kc], bX, acc[1][pj], 0, 0, 0);
        }
    }
    // phase 1: drain Xi
    asm volatile("s_waitcnt vmcnt(0)" ::: "memory");
    __builtin_amdgcn_s_barrier();
    __builtin_amdgcn_sched_barrier(0);
    #pragma unroll
    for (int kc = 4; kc < 8; ++kc) {
        #pragma unroll
        for (int pj = 0; pj < 8; ++pj) {
            int p = pj * 16 + ln;
            int cidx = (kc & 3) * 4 + q;
            short8 bX = *(const short8*)&sX[16384 + p * 128 + ((cidx ^ (p & 7)) << 3)];
            acc[0][pj] = __builtin_amdgcn_mfma_f32_16x16x32_bf16(aF[0][kc], bX, acc[0][pj], 0, 0, 0);
            acc[1][pj] = __builtin_amdgcn_mfma_f32_16x16x32_bf16(aF[1][kc], bX, acc[1][pj], 0, 0, 0);
        }
    }

    // --- epilogue: g = relu(acc + Bc[o]); C/D layout: col = ln (p), row = q*4+r (o within 16)
    float bc[2][4];
    #pragma unroll
    for (int ot = 0; ot < 2; ++ot)
        #pragma unroll
        for (int r = 0; r < 4; ++r)
            bc[ot][r] = Bc[wave * 32 + ot * 16 + q * 4 + r];

    float rs[2][4], rm[2][4], ps[8], pm[8];
    #pragma unroll
    for (int ot = 0; ot < 2; ++ot)
        #pragma unroll
        for (int r = 0; r < 4; ++r) { rs[ot][r] = 0.f; rm[ot][r] = 0.f; }
    #pragma unroll
    for (int pj = 0; pj < 8; ++pj) { ps[pj] = 0.f; pm[pj] = 0.f; }

    #pragma unroll
    for (int ot = 0; ot < 2; ++ot)
        #pragma unroll
        for (int pj = 0; pj < 8; ++pj) {
            floatx4 a = acc[ot][pj];
            #pragma unroll
            for (int r = 0; r < 4; ++r) {
                float g = fmaxf(a[r] + bc[ot][r], 0.f);
                rs[ot][r] += g;
                rm[ot][r] = fmaxf(rm[ot][r], g);
                ps[pj] += g;
                pm[pj] = fmaxf(pm[pj], g);
            }
        }

    // per-o: reduce over the 16 lanes of each quad (cols) -> atomics
    #pragma unroll
    for (int ot = 0; ot < 2; ++ot)
        #pragma unroll
        for (int r = 0; r < 4; ++r)
            #pragma unroll
            for (int off = 1; off < 16; off <<= 1) {
                rs[ot][r] += __shfl_xor(rs[ot][r], off, 64);
                rm[ot][r] = fmaxf(rm[ot][r], __shfl_xor(rm[ot][r], off, 64));
            }
    if (ln == 0) {
        #pragma unroll
        for (int ot = 0; ot < 2; ++ot)
            #pragma unroll
            for (int r = 0; r < 4; ++r) {
                int o = wave * 32 + ot * 16 + q * 4 + r;
                atomicAdd(&avgsum[n * CCH + o], rs[ot][r]);
                atomicMax(&maxbits[n * CCH + o], __float_as_uint(rm[ot][r]));  // g >= 0
            }
    }

    // per-p: reduce over q (rows within wave), then across waves via LDS
    #pragma unroll
    for (int pj = 0; pj < 8; ++pj) {
        #pragma unroll
        for (int off = 16; off < 64; off <<= 1) {
            ps[pj] += __shfl_xor(ps[pj], off, 64);
            pm[pj] = fmaxf(pm[pj], __shfl_xor(pm[pj], off, 64));
        }
    }
    __syncthreads();                       // all waves done reading sX
    float* redS = (float*)sX;              // [4 waves][128 p]
    float* redM = redS + 512;
    if (lane < 16) {
        #pragma unroll
        for (int pj = 0; pj < 8; ++pj) {
            redS[wave * 128 + pj * 16 + ln] = ps[pj];
            redM[wave * 128 + pj * 16 + ln] = pm[pj];
        }
    }
    __syncthreads();
    if (tid < 128) {
        float s = 0.f, m = 0.f;
        #pragma unroll
        for (int w = 0; w < 4; ++w) {
            s += redS[w * 128 + tid];
            m = fmaxf(m, redM[w * 128 + tid]);
        }
        spmean[(size_t)n * HW + p0 + tid] = s * (1.0f / CCH);
        spmax [(size_t)n * HW + p0 + tid] = m;
    }
}

// ---------------------------------------------------------------- channel attention (CBAM-style MLP)
__global__ void k_ca(const float* __restrict__ avgsum, const uint_t* __restrict__ maxbits,
                     const float* __restrict__ w1, const float* __restrict__ w2,
                     float* __restrict__ ca) {
    int n = blockIdx.x;
    int t = threadIdx.x;            // 128
    __shared__ float tsum[CR];
    if (t < CR) {
        float a = 0.f, m = 0.f;
        const float* w = w1 + t * CCH;
        for (int c = 0; c < CCH; c++) {
            a += w[c] * (avgsum[n * CCH + c] * (1.0f / HW));
            m += w[c] * __uint_as_float(maxbits[n * CCH + c]);
        }
        tsum[t] = fmaxf(a, 0.f) + fmaxf(m, 0.f);
    }
    __syncthreads();
    float s = 0.f;
    #pragma unroll
    for (int j = 0; j < CR; j++) s += w2[t * CR + j] * tsum[j];
    ca[n * CCH + t] = sigmoidf_(s);
}

// ---------------------------------------------------------------- 7x7 spatial-attention conv
__global__ void k_sa(const float* __restrict__ spmean, const float* __restrict__ spmax,
                     const float* __restrict__ sw, float* __restrict__ sa) {
    int b = blockIdx.x;             // n*64 + yhalf
    int n = b >> 6;
    int y = ((b & 63) << 1) | (threadIdx.x >> 7);
    int x = threadIdx.x & 127;
    float acc = 0.f;
    for (int dy = -3; dy <= 3; dy++) {
        int yy = y + dy;
        if ((unsigned)yy >= 128u) continue;
        const float* rm = spmean + (size_t)n * HW + yy * 128;
        const float* rx = spmax  + (size_t)n * HW + yy * 128;
        #pragma unroll
        for (int dx = -3; dx <= 3; dx++) {
            int xx = x + dx;
            if ((unsigned)xx < 128u) {
                float wm = sw[(dy + 3) * 7 + (dx + 3)];
                float wx = sw[49 + (dy + 3) * 7 + (dx + 3)];
                acc += wm * rm[xx] + wx * rx[xx];
            }
        }
    }
    sa[(size_t)n * HW + y * 128 + x] = sigmoidf_(acc);
}

// ---------------------------------------------------------------- final blend
// coalesced: thread reads [i] and [i+256] (both within the same 4096-f4 plane)
__global__ void k_out(const float4* __restrict__ fvi, const float4* __restrict__ fir,
                      const float* __restrict__ wch, const float* __restrict__ ca,
                      const float4* __restrict__ sa, float4* __restrict__ out) {
    size_t i0 = (size_t)blockIdx.x * 512 + threadIdx.x;
    size_t i1 = i0 + 256;
    int nc  = (int)(i0 >> 12);      // same for i1 (512-aligned chunks don't straddle planes)
    int n   = nc >> 7;
    int p40 = (int)(i0 & 4095);
    float4 a0 = fvi[i0], a1 = fvi[i1];
    float4 b0 = fir[i0], b1 = fir[i1];
    float4 s0 = sa[(size_t)n * 4096 + p40];
    float4 s1 = sa[(size_t)n * 4096 + p40 + 256];
    float u  = wch[nc];
    float cv = ca[nc];
    float4 o0, o1;
    {
        float w = sigmoidf_(s0.x * cv);
        o0.x = w * (b0.x * u + a0.x) + (1.f - w) * (a0.x * u + b0.x);
    }
    {
        float w = sigmoidf_(s0.y * cv);
        o0.y = w * (b0.y * u + a0.y) + (1.f - w) * (a0.y * u + b0.y);
    }
    {
        float w = sigmoidf_(s0.z * cv);
        o0.z = w * (b0.z * u + a0.z) + (1.f - w) * (a0.z * u + b0.z);
    }
    {
        float w = sigmoidf_(s0.w * cv);
        o0.w = w * (b0.w * u + a0.w) + (1.f - w) * (a0.w * u + b0.w);
    }
    {
        float w = sigmoidf_(s1.x * cv);
        o1.x = w * (b1.x * u + a1.x) + (1.f - w) * (a1.x * u + b1.x);
    }
    {
        float w = sigmoidf_(s1.y * cv);
        o1.y = w * (b1.y * u + a1.y) + (1.f - w) * (a1.y * u + b1.y);
    }
    {
        float w = sigmoidf_(s1.z * cv);
        o1.z = w * (b1.z * u + a1.z) + (1.f - w) * (a1.z * u + b1.z);
    }
    {
        float w = sigmoidf_(s1.w * cv);
        o1.w = w * (b1.w * u + a1.w) + (1.f - w) * (a1.w * u + b1.w);
    }
    out[i0] = o0;
    out[i1] = o1;
}

// ----------------------------------------------------------------
extern "C" void kernel_launch(void* const* d_in, const int* in_sizes, int n_in,
                              void* d_out, int out_size, void* d_ws, size_t ws_size,
                              hipStream_t stream) {
    const float* fvi     = (const float*)d_in[0];
    const float* fir     = (const float*)d_in[1];
    const float* ca1_w   = (const float*)d_in[2];
    const float* ca1_b   = (const float*)d_in[3];
    const float* bn_a_g  = (const float*)d_in[4];
    const float* bn_a_b  = (const float*)d_in[5];
    const float* bn_a_m  = (const float*)d_in[6];
    const float* bn_a_v  = (const float*)d_in[7];
    const float* ca2_w   = (const float*)d_in[8];
    const float* ca2_b   = (const float*)d_in[9];
    const float* bn_b_g  = (const float*)d_in[10];
    const float* bn_b_b  = (const float*)d_in[11];
    const float* bn_b_m  = (const float*)d_in[12];
    const float* bn_b_v  = (const float*)d_in[13];
    const float* conv1_w = (const float*)d_in[14];
    const float* conv1_b = (const float*)d_in[15];
    const float* bn_c_g  = (const float*)d_in[16];
    const float* bn_c_b  = (const float*)d_in[17];
    const float* bn_c_m  = (const float*)d_in[18];
    const float* bn_c_v  = (const float*)d_in[19];
    const float* chatt_w1 = (const float*)d_in[20];
    const float* chatt_w2 = (const float*)d_in[21];
    const float* sa_w     = (const float*)d_in[22];

    float* ws  = (float*)d_ws;
    float* out = (float*)d_out;
    ushort_t* blob = (ushort_t*)d_out;   // 134,217,728 B == out_size: d_out doubles as blob scratch
                                         // (k_conv reads it; k_out overwrites it last)

    k_zero<<<16, 256, 0, stream>>>(ws + WS_POOLED);
    k_prep<<<NB * 128 * 2, 256, 0, stream>>>(fvi, fir, blob, ws + WS_POOLED);
    k_wch<<<NB, 128, 0, stream>>>(ws + WS_POOLED, ca1_w, ca1_b,
                                  bn_a_g, bn_a_b, bn_a_m, bn_a_v,
                                  ca2_w, ca2_b, bn_b_g, bn_b_b, bn_b_m, bn_b_v,
                                  ws + WS_WCH);
    k_mkweights<<<NB * CCH, 128, 0, stream>>>(ws + WS_WCH, conv1_w,
                                              bn_c_g, bn_c_b, bn_c_m, bn_c_v, conv1_b,
                                              (ushort_t*)(ws + WS_WV), (ushort_t*)(ws + WS_WI),
                                              ws + WS_BC, ws + WS_AVGS);
    k_conv_reduce<<<NB * (HW / 128), 256, 0, stream>>>(blob,
                                                       (const ushort_t*)(ws + WS_WV),
                                                       (const ushort_t*)(ws + WS_WI),
                                                       ws + WS_BC,
                                                       ws + WS_AVGS, (uint_t*)(ws + WS_MAXB),
                                                       ws + WS_SPMEAN, ws + WS_SPMAX);
    k_ca<<<NB, 128, 0, stream>>>(ws + WS_AVGS, (const uint_t*)(ws + WS_MAXB),
                                 chatt_w1, chatt_w2, ws + WS_CA);
    k_sa<<<NB * 64, 256, 0, stream>>>(ws + WS_SPMEAN, ws + WS_SPMAX, sa_w, ws + WS_SA);
    k_out<<<(NB * CCH * HW / 4) / 512, 256, 0, stream>>>((const float4*)fvi, (const float4*)fir,
                                                         ws + WS_WCH, ws + WS_CA,
                                                         (const float4*)(ws + WS_SA), (float4*)out);
}

// Round 3
// 506.391 us; speedup vs baseline: 1.6272x; 1.6272x over previous
//
#include <hip/hip_runtime.h>
#include <math.h>

#define CCH   128        // C
#define C2    64         // C/2
#define C2X   256        // 2C
#define CR    8          // C/16
#define HW    16384
#define NB    16
#define EPSB  1e-5f

// workspace layout (float offsets) -- blob lives in d_out, NOT here
#define WS_POOLED 0          // 4096
#define WS_WCH    4096       // 2048
#define WS_AVGS   6144       // 2048
#define WS_MAXB   8192       // 2048 (uint bits)
#define WS_CA     10240      // 2048
#define WS_BC     12288      // 128
#define WS_WV     16384      // 131072 floats worth (262144 bf16)  [n][o][c]
#define WS_WI     147456     // 131072
#define WS_SPMEAN 278528     // 262144
#define WS_SPMAX  540672     // 262144
#define WS_SA     802816     // 262144

typedef short short8 __attribute__((ext_vector_type(8)));
typedef float floatx4 __attribute__((ext_vector_type(4)));
typedef unsigned short ushort_t;
typedef unsigned int uint_t;

#define GAS __attribute__((address_space(1)))
#define LAS __attribute__((address_space(3)))

__device__ __forceinline__ void gload16(const void* g, void* l) {
    __builtin_amdgcn_global_load_lds((const GAS void*)g, (LAS void*)l, 16, 0, 0);
}

__device__ __forceinline__ float sigmoidf_(float x) {
    return 1.0f / (1.0f + __expf(-x));
}

// fp32 -> bf16 with round-to-nearest-even
__device__ __forceinline__ uint_t f2bf(float f) {
    uint_t u = __float_as_uint(f);
    return (u + 0x7FFFu + ((u >> 16) & 1u)) >> 16;
}
__device__ __forceinline__ uint_t pack2bf(float a, float b) {
    return f2bf(a) | (f2bf(b) << 16);
}

// two-sided XOR swizzle: chunk slot for chunk m at pixel-row p, tile-parity par.
// Chosen so BOTH prep's b128 writes (lanes vary p = 4l+i) AND conv's b128 reads
// (lanes vary p = 16*pj+ln) spread over all 8 bank-quads (baseline-clean).
__device__ __forceinline__ int swz(int m, int p, int par) {
    return m ^ ((p ^ (p >> 3)) & 7) ^ (par << 2);
}

// ---------------------------------------------------------------- zero pooled accumulator
__global__ void k_zero(float* __restrict__ p) {
    p[blockIdx.x * 256 + threadIdx.x] = 0.f;
}

// ---------------------------------------------------------------- fused pool + bf16 cast + transpose
// Block = (n, st, g): 128 channels x 256 pixels (2 pt-tiles). LINEAR global reads:
// each load instr = one full 1 KB channel-row run (the strided-tile pattern caps at
// ~1.3 TB/s; linear runs at 4-6 TB/s). Transpose is in-register: per i-iter a thread
// holds 8 channels x 4 pixels -> packs 16B blob chunks, zero shuffles. Pooling is
// computed from the bf16 LDS image afterwards (2-way-bank u32 reads, fp32 accum).
__global__ __launch_bounds__(256)
void k_prep(const float* __restrict__ fvi, const float* __restrict__ fir,
            ushort_t* __restrict__ blob, float* __restrict__ pooled) {
    int b  = blockIdx.x;              // ((n*2 + st)*64 + g)
    int g  = b & 63;
    int st = (b >> 6) & 1;
    int n  = b >> 7;
    const float* src = (st == 0 ? fvi : fir) + (size_t)n * CCH * HW + g * 256;

    __shared__ __align__(16) ushort_t img[2 * 128 * 128];   // 64 KB: 2 pt-tile images
    __shared__ float psum[64][4][2];                        // 2 KB pool partials

    int t    = threadIdx.x;
    int wave = t >> 6;
    int lane = t & 63;

    // ---- build img: wave w handles chunks k = 4i+w (channels 8k..8k+7)
    for (int i = 0; i < 4; ++i) {
        int k = 4 * i + wave;                     // chunk id 0..15
        float4 v[8];
        #pragma unroll
        for (int j = 0; j < 8; ++j)               // 8 independent 1KB-contiguous row reads
            v[j] = *(const float4*)(src + (size_t)(8 * k + j) * HW + lane * 4);
        #pragma unroll
        for (int ii = 0; ii < 4; ++ii) {          // 4 pixels per thread
            int p  = lane * 4 + ii;               // 0..255
            int pl = p >> 7;                      // tile half (parity of pt)
            int ph = p & 127;
            uint4 pk;
            pk.x = pack2bf(((const float*)&v[0])[ii], ((const float*)&v[1])[ii]);
            pk.y = pack2bf(((const float*)&v[2])[ii], ((const float*)&v[3])[ii]);
            pk.z = pack2bf(((const float*)&v[4])[ii], ((const float*)&v[5])[ii]);
            pk.w = pack2bf(((const float*)&v[6])[ii], ((const float*)&v[7])[ii]);
            *(uint4*)&img[pl * 16384 + ph * 128 + (swz(k, ph, pl) << 3)] = pk;
        }
    }
    __syncthreads();

    // ---- dump both 32KB tiles linearly (coalesced 16B/lane)
    {
        ushort_t* d0 = blob + ((size_t)((n * 128 + 2 * g + 0) * 2 + st)) * 16384;
        ushort_t* d1 = blob + ((size_t)((n * 128 + 2 * g + 1) * 2 + st)) * 16384;
        #pragma unroll
        for (int it = 0; it < 8; ++it) {
            int off = (it * 256 + t) * 8;
            *(uint4*)&d0[off] = *(const uint4*)&img[off];
            *(uint4*)&d1[off] = *(const uint4*)&img[16384 + off];
        }
    }

    // ---- pooling from bf16 image: thread owns channel-pair slot s over 64 pixels
    {
        int s   = t & 63;                 // u32 slot: chunk m = s>>2, dword dw = s&3
        int ph4 = t >> 6;
        int m = s >> 2, dw = s & 3;
        float s0 = 0.f, s1 = 0.f;
        #pragma unroll
        for (int ii = 0; ii < 64; ++ii) {
            int pidx = ph4 * 64 + ii;     // 0..255
            int pl = pidx >> 7, p = pidx & 127;
            uint_t u = *(const uint_t*)&img[pl * 16384 + p * 128 + (swz(m, p, pl) << 3) + dw * 2];
            s0 += __uint_as_float(u << 16);           // channel 8m+2dw
            s1 += __uint_as_float(u & 0xffff0000u);   // channel 8m+2dw+1
        }
        psum[s][ph4][0] = s0;
        psum[s][ph4][1] = s1;
    }
    __syncthreads();
    if (t < 128) {                        // channel c = t
        int m = t >> 3, j = t & 7;
        int s = m * 4 + (j >> 1), par = j & 1;
        float tot = psum[s][0][par] + psum[s][1][par] + psum[s][2][par] + psum[s][3][par];
        atomicAdd(&pooled[n * 256 + st * 128 + t], tot * (1.0f / HW));
    }
}

// ---------------------------------------------------------------- channel-attention MLP -> wch
__global__ void k_wch(const float* __restrict__ pooled,
                      const float* __restrict__ ca1_w, const float* __restrict__ ca1_b,
                      const float* __restrict__ ag, const float* __restrict__ ab,
                      const float* __restrict__ am, const float* __restrict__ av,
                      const float* __restrict__ ca2_w, const float* __restrict__ ca2_b,
                      const float* __restrict__ bg, const float* __restrict__ bb,
                      const float* __restrict__ bm, const float* __restrict__ bv,
                      float* __restrict__ wch) {
    int n = blockIdx.x;
    int t = threadIdx.x;            // 128 threads
    __shared__ float h[C2];
    if (t < C2) {
        float acc = ca1_b[t];
        const float* w = ca1_w + t * C2X;
        const float* p = pooled + n * C2X;
        for (int k = 0; k < C2X; k++) acc += w[k] * p[k];
        float s = ag[t] * rsqrtf(av[t] + EPSB);
        acc = (acc - am[t]) * s + ab[t];
        h[t] = fmaxf(acc, 0.f);
    }
    __syncthreads();
    float acc = ca2_b[t];
    const float* w = ca2_w + t * C2;
    for (int j = 0; j < C2; j++) acc += w[j] * h[j];
    float s = bg[t] * rsqrtf(bv[t] + EPSB);
    acc = (acc - bm[t]) * s + bb[t];
    wch[n * CCH + t] = sigmoidf_(acc);
}

// ---------------------------------------------------------------- per-batch effective bf16 conv weights
__global__ void k_mkweights(const float* __restrict__ wch, const float* __restrict__ conv1_w,
                            const float* __restrict__ cg, const float* __restrict__ cb,
                            const float* __restrict__ cm, const float* __restrict__ cv,
                            const float* __restrict__ conv1_b,
                            ushort_t* __restrict__ Wv, ushort_t* __restrict__ Wi,
                            float* __restrict__ Bc, float* __restrict__ zeroreg) {
    int b = blockIdx.x;             // n*128 + o
    int t = threadIdx.x;            // 128 = c
    if (b < 16) { zeroreg[b * 256 + t] = 0.f; zeroreg[b * 256 + 128 + t] = 0.f; }
    if (b == 16) {
        float A = cg[t] * rsqrtf(cv[t] + EPSB);
        Bc[t] = A * (conv1_b[t] - cm[t]) + cb[t];
    }
    int n = b >> 7, o = b & 127;
    float A  = cg[o] * rsqrtf(cv[o] + EPSB);
    float u  = wch[n * CCH + t];
    float w0 = conv1_w[o * C2X + t];
    float w1 = conv1_w[o * C2X + t + CCH];
    Wv[(size_t)b * CCH + t] = (ushort_t)f2bf(A * (w0 + u * w1));
    Wi[(size_t)b * CCH + t] = (ushort_t)f2bf(A * (w1 + u * w0));
}

// ---------------------------------------------------------------- fused conv1x1+bn+relu + reductions (MFMA)
// A-frags (weights) in registers from L2-hot Wv/Wi; X arrives via LINEAR
// global_load_lds DMA of the pre-swizzled blob (64 KB per block); counted
// vmcnt(8) + raw s_barrier keeps the Xi half in flight under the Xv compute.
__global__ __launch_bounds__(256)
void k_conv_reduce(const ushort_t* __restrict__ blob,
                   const ushort_t* __restrict__ Wv, const ushort_t* __restrict__ Wi,
                   const float* __restrict__ Bc,
                   float* __restrict__ avgsum, uint_t* __restrict__ maxbits,
                   float* __restrict__ spmean, float* __restrict__ spmax) {
    int n  = blockIdx.x >> 7;
    int pt = blockIdx.x & 127;
    int p0 = pt * 128;
    int par = pt & 1;
    __shared__ __align__(16) ushort_t sX[32768];   // 64 KB: Xv [0,16384), Xi [16384,32768)
    int tid  = threadIdx.x;
    int wave = tid >> 6;
    int lane = tid & 63;
    int q    = lane >> 4;
    int ln   = lane & 15;

    // ---- A fragments straight to registers (each byte of 64 KB read once per block, L2-hot)
    short8 aF[2][8];
    {
        const ushort_t* wv = Wv + (size_t)n * 16384;
        const ushort_t* wi = Wi + (size_t)n * 16384;
        #pragma unroll
        for (int kc = 0; kc < 8; ++kc) {
            const ushort_t* ws_ = (kc < 4) ? wv : wi;
            #pragma unroll
            for (int ot = 0; ot < 2; ++ot) {
                int o = wave * 32 + ot * 16 + ln;
                aF[ot][kc] = *(const short8*)&ws_[(size_t)o * 128 + (kc & 3) * 32 + q * 8];
            }
        }
    }
    __builtin_amdgcn_sched_barrier(0);    // pin: A-loads issue before the DMAs (vmcnt counting)
    // ---- async DMA: blob(n,pt) 64 KB -> LDS, Xv issues first, then Xi
    {
        const ushort_t* gb = blob + (((size_t)(n * 128 + pt)) << 15) + wave * 512 + lane * 8;
        ushort_t* lb = &sX[wave * 512];
        #pragma unroll
        for (int i = 0; i < 16; ++i)
            gload16(gb + i * 2048, lb + i * 2048);
    }
    __builtin_amdgcn_sched_barrier(0);

    floatx4 acc[2][8];
    #pragma unroll
    for (int a = 0; a < 2; a++)
        #pragma unroll
        for (int c = 0; c < 8; c++) acc[a][c] = (floatx4){0.f, 0.f, 0.f, 0.f};

    // phase 0: A(16)+DMA(16) outstanding; vmcnt(8) -> A done + Xv landed, Xi in flight
    asm volatile("s_waitcnt vmcnt(8)" ::: "memory");
    __builtin_amdgcn_s_barrier();
    __builtin_amdgcn_sched_barrier(0);
    #pragma unroll
    for (int kc = 0; kc < 4; ++kc) {
        #pragma unroll
        for (int pj = 0; pj < 8; ++pj) {
            int p = pj * 16 + ln;
            int cidx = kc * 4 + q;
            short8 bX = *(const short8*)&sX[p * 128 + (swz(cidx, p, par) << 3)];
            acc[0][pj] = __builtin_amdgcn_mfma_f32_16x16x32_bf16(aF[0][kc], bX, acc[0][pj], 0, 0, 0);
            acc[1][pj] = __builtin_amdgcn_mfma_f32_16x16x32_bf16(aF[1][kc], bX, acc[1][pj], 0, 0, 0);
        }
    }
    // phase 1: drain Xi
    asm volatile("s_waitcnt vmcnt(0)" ::: "memory");
    __builtin_amdgcn_s_barrier();
    __builtin_amdgcn_sched_barrier(0);
    #pragma unroll
    for (int kc = 4; kc < 8; ++kc) {
        #pragma unroll
        for (int pj = 0; pj < 8; ++pj) {
            int p = pj * 16 + ln;
            int cidx = (kc & 3) * 4 + q;
            short8 bX = *(const short8*)&sX[16384 + p * 128 + (swz(cidx, p, par) << 3)];
            acc[0][pj] = __builtin_amdgcn_mfma_f32_16x16x32_bf16(aF[0][kc], bX, acc[0][pj], 0, 0, 0);
            acc[1][pj] = __builtin_amdgcn_mfma_f32_16x16x32_bf16(aF[1][kc], bX, acc[1][pj], 0, 0, 0);
        }
    }

    // --- epilogue: g = relu(acc + Bc[o]); C/D layout: col = ln (p), row = q*4+r (o within 16)
    float bc[2][4];
    #pragma unroll
    for (int ot = 0; ot < 2; ++ot)
        #pragma unroll
        for (int r = 0; r < 4; ++r)
            bc[ot][r] = Bc[wave * 32 + ot * 16 + q * 4 + r];

    float rs[2][4], rm[2][4], ps[8], pm[8];
    #pragma unroll
    for (int ot = 0; ot < 2; ++ot)
        #pragma unroll
        for (int r = 0; r < 4; ++r) { rs[ot][r] = 0.f; rm[ot][r] = 0.f; }
    #pragma unroll
    for (int pj = 0; pj < 8; ++pj) { ps[pj] = 0.f; pm[pj] = 0.f; }

    #pragma unroll
    for (int ot = 0; ot < 2; ++ot)
        #pragma unroll
        for (int pj = 0; pj < 8; ++pj) {
            floatx4 a = acc[ot][pj];
            #pragma unroll
            for (int r = 0; r < 4; ++r) {
                float g = fmaxf(a[r] + bc[ot][r], 0.f);
                rs[ot][r] += g;
                rm[ot][r] = fmaxf(rm[ot][r], g);
                ps[pj] += g;
                pm[pj] = fmaxf(pm[pj], g);
            }
        }

    // per-o: reduce over the 16 lanes of each quad (cols) -> atomics
    #pragma unroll
    for (int ot = 0; ot < 2; ++ot)
        #pragma unroll
        for (int r = 0; r < 4; ++r)
            #pragma unroll
            for (int off = 1; off < 16; off <<= 1) {
                rs[ot][r] += __shfl_xor(rs[ot][r], off, 64);
                rm[ot][r] = fmaxf(rm[ot][r], __shfl_xor(rm[ot][r], off, 64));
            }
    if (ln == 0) {
        #pragma unroll
        for (int ot = 0; ot < 2; ++ot)
            #pragma unroll
            for (int r = 0; r < 4; ++r) {
                int o = wave * 32 + ot * 16 + q * 4 + r;
                atomicAdd(&avgsum[n * CCH + o], rs[ot][r]);
                atomicMax(&maxbits[n * CCH + o], __float_as_uint(rm[ot][r]));  // g >= 0
            }
    }

    // per-p: reduce over q (rows within wave), then across waves via LDS
    #pragma unroll
    for (int pj = 0; pj < 8; ++pj) {
        #pragma unroll
        for (int off = 16; off < 64; off <<= 1) {
            ps[pj] += __shfl_xor(ps[pj], off, 64);
            pm[pj] = fmaxf(pm[pj], __shfl_xor(pm[pj], off, 64));
        }
    }
    __syncthreads();                       // all waves done reading sX
    float* redS = (float*)sX;              // [4 waves][128 p]
    float* redM = redS + 512;
    if (lane < 16) {
        #pragma unroll
        for (int pj = 0; pj < 8; ++pj) {
            redS[wave * 128 + pj * 16 + ln] = ps[pj];
            redM[wave * 128 + pj * 16 + ln] = pm[pj];
        }
    }
    __syncthreads();
    if (tid < 128) {
        float s = 0.f, m = 0.f;
        #pragma unroll
        for (int w = 0; w < 4; ++w) {
            s += redS[w * 128 + tid];
            m = fmaxf(m, redM[w * 128 + tid]);
        }
        spmean[(size_t)n * HW + p0 + tid] = s * (1.0f / CCH);
        spmax [(size_t)n * HW + p0 + tid] = m;
    }
}

// ---------------------------------------------------------------- channel attention (CBAM-style MLP)
__global__ void k_ca(const float* __restrict__ avgsum, const uint_t* __restrict__ maxbits,
                     const float* __restrict__ w1, const float* __restrict__ w2,
                     float* __restrict__ ca) {
    int n = blockIdx.x;
    int t = threadIdx.x;            // 128
    __shared__ float tsum[CR];
    if (t < CR) {
        float a = 0.f, m = 0.f;
        const float* w = w1 + t * CCH;
        for (int c = 0; c < CCH; c++) {
            a += w[c] * (avgsum[n * CCH + c] * (1.0f / HW));
            m += w[c] * __uint_as_float(maxbits[n * CCH + c]);
        }
        tsum[t] = fmaxf(a, 0.f) + fmaxf(m, 0.f);
    }
    __syncthreads();
    float s = 0.f;
    #pragma unroll
    for (int j = 0; j < CR; j++) s += w2[t * CR + j] * tsum[j];
    ca[n * CCH + t] = sigmoidf_(s);
}

// ---------------------------------------------------------------- 7x7 spatial-attention conv
__global__ void k_sa(const float* __restrict__ spmean, const float* __restrict__ spmax,
                     const float* __restrict__ sw, float* __restrict__ sa) {
    int b = blockIdx.x;             // n*64 + yhalf
    int n = b >> 6;
    int y = ((b & 63) << 1) | (threadIdx.x >> 7);
    int x = threadIdx.x & 127;
    float acc = 0.f;
    for (int dy = -3; dy <= 3; dy++) {
        int yy = y + dy;
        if ((unsigned)yy >= 128u) continue;
        const float* rm = spmean + (size_t)n * HW + yy * 128;
        const float* rx = spmax  + (size_t)n * HW + yy * 128;
        #pragma unroll
        for (int dx = -3; dx <= 3; dx++) {
            int xx = x + dx;
            if ((unsigned)xx < 128u) {
                float wm = sw[(dy + 3) * 7 + (dx + 3)];
                float wx = sw[49 + (dy + 3) * 7 + (dx + 3)];
                acc += wm * rm[xx] + wx * rx[xx];
            }
        }
    }
    sa[(size_t)n * HW + y * 128 + x] = sigmoidf_(acc);
}

// ---------------------------------------------------------------- final blend
// coalesced: thread reads [i] and [i+256] (both within the same 4096-f4 plane)
__global__ void k_out(const float4* __restrict__ fvi, const float4* __restrict__ fir,
                      const float* __restrict__ wch, const float* __restrict__ ca,
                      const float4* __restrict__ sa, float4* __restrict__ out) {
    size_t i0 = (size_t)blockIdx.x * 512 + threadIdx.x;
    size_t i1 = i0 + 256;
    int nc  = (int)(i0 >> 12);      // same for i1 (512-aligned chunks don't straddle planes)
    int n   = nc >> 7;
    int p40 = (int)(i0 & 4095);
    float4 a0 = fvi[i0], a1 = fvi[i1];
    float4 b0 = fir[i0], b1 = fir[i1];
    float4 s0 = sa[(size_t)n * 4096 + p40];
    float4 s1 = sa[(size_t)n * 4096 + p40 + 256];
    float u  = wch[nc];
    float cv = ca[nc];
    float4 o0, o1;
    {
        float w = sigmoidf_(s0.x * cv);
        o0.x = w * (b0.x * u + a0.x) + (1.f - w) * (a0.x * u + b0.x);
    }
    {
        float w = sigmoidf_(s0.y * cv);
        o0.y = w * (b0.y * u + a0.y) + (1.f - w) * (a0.y * u + b0.y);
    }
    {
        float w = sigmoidf_(s0.z * cv);
        o0.z = w * (b0.z * u + a0.z) + (1.f - w) * (a0.z * u + b0.z);
    }
    {
        float w = sigmoidf_(s0.w * cv);
        o0.w = w * (b0.w * u + a0.w) + (1.f - w) * (a0.w * u + b0.w);
    }
    {
        float w = sigmoidf_(s1.x * cv);
        o1.x = w * (b1.x * u + a1.x) + (1.f - w) * (a1.x * u + b1.x);
    }
    {
        float w = sigmoidf_(s1.y * cv);
        o1.y = w * (b1.y * u + a1.y) + (1.f - w) * (a1.y * u + b1.y);
    }
    {
        float w = sigmoidf_(s1.z * cv);
        o1.z = w * (b1.z * u + a1.z) + (1.f - w) * (a1.z * u + b1.z);
    }
    {
        float w = sigmoidf_(s1.w * cv);
        o1.w = w * (b1.w * u + a1.w) + (1.f - w) * (a1.w * u + b1.w);
    }
    out[i0] = o0;
    out[i1] = o1;
}

// ----------------------------------------------------------------
extern "C" void kernel_launch(void* const* d_in, const int* in_sizes, int n_in,
                              void* d_out, int out_size, void* d_ws, size_t ws_size,
                              hipStream_t stream) {
    const float* fvi     = (const float*)d_in[0];
    const float* fir     = (const float*)d_in[1];
    const float* ca1_w   = (const float*)d_in[2];
    const float* ca1_b   = (const float*)d_in[3];
    const float* bn_a_g  = (const float*)d_in[4];
    const float* bn_a_b  = (const float*)d_in[5];
    const float* bn_a_m  = (const float*)d_in[6];
    const float* bn_a_v  = (const float*)d_in[7];
    const float* ca2_w   = (const float*)d_in[8];
    const float* ca2_b   = (const float*)d_in[9];
    const float* bn_b_g  = (const float*)d_in[10];
    const float* bn_b_b  = (const float*)d_in[11];
    const float* bn_b_m  = (const float*)d_in[12];
    const float* bn_b_v  = (const float*)d_in[13];
    const float* conv1_w = (const float*)d_in[14];
    const float* conv1_b = (const float*)d_in[15];
    const float* bn_c_g  = (const float*)d_in[16];
    const float* bn_c_b  = (const float*)d_in[17];
    const float* bn_c_m  = (const float*)d_in[18];
    const float* bn_c_v  = (const float*)d_in[19];
    const float* chatt_w1 = (const float*)d_in[20];
    const float* chatt_w2 = (const float*)d_in[21];
    const float* sa_w     = (const float*)d_in[22];

    float* ws  = (float*)d_ws;
    float* out = (float*)d_out;
    ushort_t* blob = (ushort_t*)d_out;   // d_out doubles as blob scratch
                                         // (k_conv reads it; k_out overwrites it last)

    k_zero<<<16, 256, 0, stream>>>(ws + WS_POOLED);
    k_prep<<<NB * 2 * 64, 256, 0, stream>>>(fvi, fir, blob, ws + WS_POOLED);
    k_wch<<<NB, 128, 0, stream>>>(ws + WS_POOLED, ca1_w, ca1_b,
                                  bn_a_g, bn_a_b, bn_a_m, bn_a_v,
                                  ca2_w, ca2_b, bn_b_g, bn_b_b, bn_b_m, bn_b_v,
                                  ws + WS_WCH);
    k_mkweights<<<NB * CCH, 128, 0, stream>>>(ws + WS_WCH, conv1_w,
                                              bn_c_g, bn_c_b, bn_c_m, bn_c_v, conv1_b,
                                              (ushort_t*)(ws + WS_WV), (ushort_t*)(ws + WS_WI),
                                              ws + WS_BC, ws + WS_AVGS);
    k_conv_reduce<<<NB * (HW / 128), 256, 0, stream>>>(blob,
                                                       (const ushort_t*)(ws + WS_WV),
                                                       (const ushort_t*)(ws + WS_WI),
                                                       ws + WS_BC,
                                                       ws + WS_AVGS, (uint_t*)(ws + WS_MAXB),
                                                       ws + WS_SPMEAN, ws + WS_SPMAX);
    k_ca<<<NB, 128, 0, stream>>>(ws + WS_AVGS, (const uint_t*)(ws + WS_MAXB),
                                 chatt_w1, chatt_w2, ws + WS_CA);
    k_sa<<<NB * 64, 256, 0, stream>>>(ws + WS_SPMEAN, ws + WS_SPMAX, sa_w, ws + WS_SA);
    k_out<<<(NB * CCH * HW / 4) / 512, 256, 0, stream>>>((const float4*)fvi, (const float4*)fir,
                                                         ws + WS_WCH, ws + WS_CA,
                                                         (const float4*)(ws + WS_SA), (float4*)out);
}